// Round 2
// baseline (208.225 us; speedup 1.0000x reference)
//
#include <hip/hip_runtime.h>

// TriangleLinear: out[b][8191-r] = bias[r] + sum_{c>=max(0,r-4)} W_packed[...] * x[b][c]
// HBM-bound on the 134.4 MB packed-weight stream (read exactly once) => ~21 us floor.
//
// R2 theory: R1's weight loads were stride-16B per instruction (c = cb + 4t + j:
// 64 lanes x 16B stride = 16 lines/instr, 16B used per line) AND nontemporal
// (no-allocate) -> the 4 j-instructions over the same 1KB span each re-fetched the
// lines from HBM => ~4x over-fetch (537 MB) at poor scattered-line efficiency
// ~= the measured 197 us. Fix: column mapping c = cb + t + 256*j so EVERY load
// instruction (w and x) is a 64-lane x 4B = 256B contiguous burst (4 full lines,
// all bytes used), and drop nontemporal so L1/L2 fetch each line exactly once.
// (R3 = R2 resubmitted: previous round's container failure was infrastructure,
// no measurement was produced.)

constexpr int N = 8192;      // N_IN == N_OUT
constexpr int BATCH = 8;
constexpr int ROWS = 4;      // rows per block: x loads shared across rows in registers
constexpr int THREADS = 256;
constexpr int VEC = 4;       // columns per thread (strided by THREADS, not packed)
constexpr int TILE = THREADS * VEC;  // 1024 columns per block-iteration

__global__ __launch_bounds__(THREADS, 4)
void tri_linear_kernel(const float* __restrict__ x,
                       const float* __restrict__ w,
                       const float* __restrict__ bias,
                       float* __restrict__ out) {
  const int t = threadIdx.x;
  const int r0 = blockIdx.x * ROWS;

  // Per-row triangular start column and packed-row base pointers (uniform -> SGPR).
  int c0[ROWS];
  const float* wrow[ROWS];
#pragma unroll
  for (int i = 0; i < ROWS; ++i) {
    const int r = r0 + i;
    c0[i] = (r > 4) ? (r - 4) : 0;
    // off(r) = 8192*r - (r-5)(r-4)/2 for r>=5, else 8192*r. (off(8192)=33,591,286 = nW)
    long long off = (r <= 5)
        ? (long long)r * N
        : (long long)r * N - ((long long)(r - 5) * (long long)(r - 4)) / 2;
    wrow[i] = w + (off - (long long)c0[i]);   // wrow[i][c] valid for c in [c0[i], N)
  }
  const int cbA = c0[0] & ~(TILE - 1);        // c0[0] == min c0 of this block's rows

  float acc[ROWS][BATCH];
#pragma unroll
  for (int i = 0; i < ROWS; ++i)
#pragma unroll
    for (int b = 0; b < BATCH; ++b) acc[i][b] = 0.0f;

  // ---- Edge tile [cbA, cbA+TILE): predicated on the triangular boundary ----
  // Safe: c0[0] = 4*blockIdx-4 is a multiple of 4, so c0[i] <= cbA+1023 < cbA+TILE
  // (all triangular starts fall inside this tile; main loop needs no predicate).
  {
#pragma unroll
    for (int j = 0; j < VEC; ++j) {
      const int c = cbA + t + j * THREADS;    // coalesced: lanes contiguous 4B
      float xv[BATCH];
#pragma unroll
      for (int b = 0; b < BATCH; ++b) xv[b] = x[b * N + c];
#pragma unroll
      for (int i = 0; i < ROWS; ++i) {
        const float wv = (c >= c0[i]) ? wrow[i][c] : 0.0f;
#pragma unroll
        for (int b = 0; b < BATCH; ++b)
          acc[i][b] = fmaf(wv, xv[b], acc[i][b]);
      }
    }
  }

  // ---- Main loop: predicate-free, every load instruction a 256B contiguous burst ----
  // Per iteration/thread: 16 w dword loads (4 SGPR bases x 4 imm offsets sharing one
  // voffset), 32 x dword loads (L1/L2-resident), 128 FMAs. All loads hoisted above
  // the FMA block by the unroll -> 48 in flight per wave, 192 per SIMD at 4 waves.
  for (int cb = cbA + TILE; cb < N; cb += TILE) {
    const int c = cb + t;
    float wv[ROWS][VEC];
#pragma unroll
    for (int i = 0; i < ROWS; ++i)
#pragma unroll
      for (int j = 0; j < VEC; ++j)
        wv[i][j] = wrow[i][c + j * THREADS];  // plain load: let L1 keep the line
    float xv[VEC][BATCH];
#pragma unroll
    for (int j = 0; j < VEC; ++j)
#pragma unroll
      for (int b = 0; b < BATCH; ++b)
        xv[j][b] = x[b * N + c + j * THREADS];
#pragma unroll
    for (int i = 0; i < ROWS; ++i)
#pragma unroll
      for (int j = 0; j < VEC; ++j)
#pragma unroll
        for (int b = 0; b < BATCH; ++b)
          acc[i][b] = fmaf(wv[i][j], xv[j][b], acc[i][b]);
  }

  // ---- Reduction: 32 (row,batch) sums over 256 threads, transposed LDS tile ----
  // red[256][33] = 33.8 KB (4 blocks/CU). Pad 33 -> write bank (t + s) % 32 (2-way,
  // free) and read bank (k + s) % 32 with s spanning 0..31 across the wave (2-way, free).
  __shared__ float red[THREADS][ROWS * BATCH + 1];
#pragma unroll
  for (int i = 0; i < ROWS; ++i)
#pragma unroll
    for (int b = 0; b < BATCH; ++b)
      red[t][i * BATCH + b] = acc[i][b];
  __syncthreads();

  const int s = t & 31;     // which (row,batch) sum
  const int part = t >> 5;  // which 32-thread chunk
  float p = 0.0f;
#pragma unroll
  for (int k = 0; k < 32; ++k) p += red[part * 32 + k][s];

  __shared__ float red2[32][9];
  red2[s][part] = p;
  __syncthreads();

  if (t < 32) {
    float total = 0.0f;
#pragma unroll
    for (int g = 0; g < 8; ++g) total += red2[t][g];
    const int i = t >> 3, b = t & 7;   // t == i*BATCH + b == s
    const int r = r0 + i;
    out[b * N + (N - 1 - r)] = total + bias[r];  // last-dim flip + bias
  }
}

extern "C" void kernel_launch(void* const* d_in, const int* in_sizes, int n_in,
                              void* d_out, int out_size, void* d_ws, size_t ws_size,
                              hipStream_t stream) {
  const float* x    = (const float*)d_in[0];  // [8, 8192]
  const float* w    = (const float*)d_in[1];  // [33591286] packed triangular
  const float* bias = (const float*)d_in[2];  // [8192]
  float* out = (float*)d_out;                 // [8, 8192]
  tri_linear_kernel<<<N / ROWS, THREADS, 0, stream>>>(x, w, bias, out);
}

// Round 3
// 206.957 us; speedup vs baseline: 1.0061x; 1.0061x over previous
//
#include <hip/hip_runtime.h>

// TriangleLinear: out[b][8191-r] = bias[r] + sum_{c>=max(0,r-4)} W_packed[...] * x[b][c]
// HBM floor: 134.4 MB packed-weight stream read once => ~21 us kernel.
//
// Measurement model (R2 post-mortem): rocprof top-5 by duration shows only the
// harness's 537 MB workspace re-poison fills (~78 us each) -> our kernel dispatch
// is < 77 us. dur_us ~= kernel + ~156 us fixed fill overhead. R1 kernel ~41 us
// (3.3 TB/s on w => latency-bound, not BW-bound), R2 ~52 us (scalarizing x doubled
// VMEM instruction count 24->48; regression).
//
// R3: back to R1's packed 4t+j mapping (x float4; w scalar, since packed triangular
// rows are only 4B-aligned so float4 w loads are UB). Changes vs R1:
//   1. Double-buffered w prefetch: next tile's 16 w loads issue before current FMAs,
//      taking the ~900cyc HBM latency off the critical path (only L2-hot x gates FMAs).
//   2. No nontemporal on w: let L1 keep each 64B line so the 4-instruction j-family
//      consumes it once (nt forced refetch of lines touched by 4 overlapping instrs).
// VGPR ~105 (acc 32 + wbuf 16 + wnext 16 + xv 32 + addr) -> fits 128 cap, 4 waves/SIMD.

constexpr int N = 8192;      // N_IN == N_OUT
constexpr int BATCH = 8;
constexpr int ROWS = 4;      // rows per block: x loads shared across rows in registers
constexpr int THREADS = 256;
constexpr int VEC = 4;       // columns per thread (packed: float4 x loads)
constexpr int TILE = THREADS * VEC;  // 1024 columns per block-iteration

__global__ __launch_bounds__(THREADS, 4)
void tri_linear_kernel(const float* __restrict__ x,
                       const float* __restrict__ w,
                       const float* __restrict__ bias,
                       float* __restrict__ out) {
  const int t = threadIdx.x;
  const int r0 = blockIdx.x * ROWS;

  // Per-row triangular start column and packed-row base pointers (uniform -> SGPR).
  int c0[ROWS];
  const float* wrow[ROWS];
#pragma unroll
  for (int i = 0; i < ROWS; ++i) {
    const int r = r0 + i;
    c0[i] = (r > 4) ? (r - 4) : 0;
    // off(r) = 8192*r - (r-5)(r-4)/2 for r>=5, else 8192*r. (off(8192)=33,591,286 = nW)
    long long off = (r <= 5)
        ? (long long)r * N
        : (long long)r * N - ((long long)(r - 5) * (long long)(r - 4)) / 2;
    wrow[i] = w + (off - (long long)c0[i]);   // wrow[i][c] valid for c in [c0[i], N)
  }
  const int cbA = c0[0] & ~(TILE - 1);        // c0[0] == min c0 of this block's rows
  // c0[0] = r0-4 is a multiple of 4, so c0[i] <= c0[0]+3 <= cbA+1023: every row's
  // triangular start falls inside the edge tile; main loop needs no predicate.

  float acc[ROWS][BATCH];
#pragma unroll
  for (int i = 0; i < ROWS; ++i)
#pragma unroll
    for (int b = 0; b < BATCH; ++b) acc[i][b] = 0.0f;

  const int c4 = VEC * t;   // this thread's packed column offset within a tile

  // ---- Edge tile [cbA, cbA+TILE): predicated on the triangular boundary ----
  {
    const int c = cbA + c4;
    float4 xv[BATCH];
#pragma unroll
    for (int b = 0; b < BATCH; ++b)
      xv[b] = *(const float4*)(x + b * N + c);
#pragma unroll
    for (int i = 0; i < ROWS; ++i) {
#pragma unroll
      for (int j = 0; j < VEC; ++j) {
        const int cj = c + j;
        const float wv = (cj >= c0[i]) ? wrow[i][cj] : 0.0f;
        const float* xe;
#pragma unroll
        for (int b = 0; b < BATCH; ++b) {
          xe = reinterpret_cast<const float*>(&xv[b]);
          acc[i][b] = fmaf(wv, xe[j], acc[i][b]);
        }
      }
    }
  }

  // ---- Main loop: predicate-free, w double-buffered one tile ahead ----
  int cb = cbA + TILE;
  if (cb < N) {
    float wbuf[ROWS][VEC];
#pragma unroll
    for (int i = 0; i < ROWS; ++i)
#pragma unroll
      for (int j = 0; j < VEC; ++j)
        wbuf[i][j] = wrow[i][cb + c4 + j];      // prologue: preload first main tile

#pragma unroll 2
    for (; cb + TILE < N; cb += TILE) {
      const int c = cb + c4;
      float4 xv[BATCH];
#pragma unroll
      for (int b = 0; b < BATCH; ++b)
        xv[b] = *(const float4*)(x + b * N + c);   // L2-hot, ~200cyc
      float wnxt[ROWS][VEC];
#pragma unroll
      for (int i = 0; i < ROWS; ++i)
#pragma unroll
        for (int j = 0; j < VEC; ++j)
          wnxt[i][j] = wrow[i][c + TILE + j];      // HBM, in flight across FMAs
#pragma unroll
      for (int i = 0; i < ROWS; ++i)
#pragma unroll
        for (int j = 0; j < VEC; ++j) {
          const float* xe;
#pragma unroll
          for (int b = 0; b < BATCH; ++b) {
            xe = reinterpret_cast<const float*>(&xv[b]);
            acc[i][b] = fmaf(wbuf[i][j], xe[j], acc[i][b]);
          }
        }
#pragma unroll
      for (int i = 0; i < ROWS; ++i)
#pragma unroll
        for (int j = 0; j < VEC; ++j)
          wbuf[i][j] = wnxt[i][j];                 // rotate (coalesced by unroll 2)
    }

    // ---- Tail tile: FMA the preloaded buffer, no further prefetch ----
    {
      const int c = cb + c4;
      float4 xv[BATCH];
#pragma unroll
      for (int b = 0; b < BATCH; ++b)
        xv[b] = *(const float4*)(x + b * N + c);
#pragma unroll
      for (int i = 0; i < ROWS; ++i)
#pragma unroll
        for (int j = 0; j < VEC; ++j) {
          const float* xe;
#pragma unroll
          for (int b = 0; b < BATCH; ++b) {
            xe = reinterpret_cast<const float*>(&xv[b]);
            acc[i][b] = fmaf(wbuf[i][j], xe[j], acc[i][b]);
          }
        }
    }
  }

  // ---- Reduction: 32 (row,batch) sums over 256 threads, transposed LDS tile ----
  // red[256][33] = 33.8 KB (4 blocks/CU). Pad 33 -> write bank (t + s) % 32 (2-way,
  // free) and read bank (k + s) % 32 with s spanning 0..31 across the wave (2-way, free).
  __shared__ float red[THREADS][ROWS * BATCH + 1];
#pragma unroll
  for (int i = 0; i < ROWS; ++i)
#pragma unroll
    for (int b = 0; b < BATCH; ++b)
      red[t][i * BATCH + b] = acc[i][b];
  __syncthreads();

  const int s = t & 31;     // which (row,batch) sum
  const int part = t >> 5;  // which 32-thread chunk
  float p = 0.0f;
#pragma unroll
  for (int k = 0; k < 32; ++k) p += red[part * 32 + k][s];

  __shared__ float red2[32][9];
  red2[s][part] = p;
  __syncthreads();

  if (t < 32) {
    float total = 0.0f;
#pragma unroll
    for (int g = 0; g < 8; ++g) total += red2[t][g];
    const int i = t >> 3, b = t & 7;   // t == i*BATCH + b == s
    const int r = r0 + i;
    out[b * N + (N - 1 - r)] = total + bias[r];  // last-dim flip + bias
  }
}

extern "C" void kernel_launch(void* const* d_in, const int* in_sizes, int n_in,
                              void* d_out, int out_size, void* d_ws, size_t ws_size,
                              hipStream_t stream) {
  const float* x    = (const float*)d_in[0];  // [8, 8192]
  const float* w    = (const float*)d_in[1];  // [33591286] packed triangular
  const float* bias = (const float*)d_in[2];  // [8192]
  float* out = (float*)d_out;                 // [8, 8192]
  tri_linear_kernel<<<N / ROWS, THREADS, 0, stream>>>(x, w, bias, out);
}